// Round 6
// baseline (138.211 us; speedup 1.0000x reference)
//
#include <hip/hip_runtime.h>

// NT-Xent: BATCH=4096, DIM=512, TEMP=0.5
// loss = mean_i [ log(sum_{j!=i} exp(2*cos(z_i,z_j))) - 2*cos(z_i, z_partner) ]
// R6: LDS-free fp8 GEMM. zq (4 MB) is L2-resident; MFMA fragments are loaded
// directly from global (2x global_load_dwordx4 per 32B operand). No staging,
// no K-loop barriers, no swizzle. Triangular blocks + fused diag-removal +
// positive-pair harvest + exp row/col sums carried over from R5.

#define NROWS 8192
#define HALF_N 4096
#define KD 512            // elements per row (= 512 B/row in fp8)
#define TILE 128
#define BK 128            // K bytes per iteration (one MFMA per tile-pair)
#define NT (NROWS / TILE) // 64 block-tiles per side

typedef unsigned char u8;
typedef __attribute__((ext_vector_type(4))) int i32x4;
typedef __attribute__((ext_vector_type(8))) int i32x8;
typedef __attribute__((ext_vector_type(4))) float f32x4;

// ---------------- normalize: z (fp32) -> zq (fp8 e4m3, unit rows) ------------
// wave-per-row: 4 rows/block, 2048 blocks. Also zeroes rowsum/possum/out.
__global__ __launch_bounds__(256) void nt_normalize(const float* __restrict__ zi,
                                                    const float* __restrict__ zj,
                                                    u8* __restrict__ zq,
                                                    float* __restrict__ rowsum,
                                                    float* __restrict__ possum,
                                                    float* __restrict__ out) {
  const int t = threadIdx.x;
  if (t < 4) rowsum[blockIdx.x * 4 + t] = 0.f;
  if (blockIdx.x == 0 && t == 4) { possum[0] = 0.f; out[0] = 0.f; }

  const int wave = t >> 6, lane = t & 63;
  const int row = blockIdx.x * 4 + wave;
  const float* src = (row < HALF_N) ? (zi + (size_t)row * KD)
                                    : (zj + (size_t)(row - HALF_N) * KD);
  const float4 v0 = ((const float4*)src)[lane * 2];
  const float4 v1 = ((const float4*)src)[lane * 2 + 1];
  float ss = v0.x * v0.x + v0.y * v0.y + v0.z * v0.z + v0.w * v0.w +
             v1.x * v1.x + v1.y * v1.y + v1.z * v1.z + v1.w * v1.w;
#pragma unroll
  for (int m = 1; m < 64; m <<= 1) ss += __shfl_xor(ss, m);
  const float inv = rsqrtf(ss);              // norms ~22.6, EPS irrelevant
  int lo = __builtin_amdgcn_cvt_pk_fp8_f32(v0.x * inv, v0.y * inv, 0, false);
  lo = __builtin_amdgcn_cvt_pk_fp8_f32(v0.z * inv, v0.w * inv, lo, true);
  int hi = __builtin_amdgcn_cvt_pk_fp8_f32(v1.x * inv, v1.y * inv, 0, false);
  hi = __builtin_amdgcn_cvt_pk_fp8_f32(v1.z * inv, v1.w * inv, hi, true);
  ((int2*)(zq + (size_t)row * KD))[lane] = make_int2(lo, hi);
}

// ---------------- GEMM + fused epilogue (upper-triangular blocks) ----------
// 128x128 tile per block, 4 waves in 2x2, each wave 4x4 MFMA tiles of 16x16,
// one mfma_scale_f32_16x16x128 per tile-pair per K-iteration (BK=128).
// Fragments loaded straight from global: lane (c16,quad) of fragment mi reads
// row (base + mi*16 + c16), bytes [k0 + quad*32, +32). Scales = 1.0 (E8M0 7F).
__global__ __launch_bounds__(256) void nt_gemm(const u8* __restrict__ zq,
                                               float* __restrict__ rowsum,
                                               float* __restrict__ possum) {
  __shared__ float lrow[TILE];
  __shared__ float lcol[TILE];

  // decode linear bid -> (tm, tn) with tn >= tm
  const int bid = blockIdx.x;
  int tm = (int)((float)(2 * NT + 1) * 0.5f -
                 sqrtf((float)(2 * NT + 1) * (float)(2 * NT + 1) * 0.25f - 2.0f * (float)bid));
  if (tm < 0) tm = 0;
  if (tm > NT - 1) tm = NT - 1;
  while ((tm + 1) * NT - ((tm + 1) * tm) / 2 <= bid) ++tm;
  while (tm * NT - (tm * (tm - 1)) / 2 > bid) --tm;
  const int tn = tm + (bid - (tm * NT - (tm * (tm - 1)) / 2));
  const bool diag = (tm == tn);
  const bool isPos = (tn - tm == 32);   // block diagonal holds sim[i][i+N]

  const int t = threadIdx.x;
  const int wave = t >> 6, lane = t & 63;
  const int wm = wave >> 1, wn = wave & 1;
  const int c16 = lane & 15, quad = lane >> 4;

  const int rowA = tm * TILE, rowB = tn * TILE;

  // per-lane fragment base pointers (row * 512 + quad*32)
  const u8* aptr[4];
  const u8* bptr[4];
#pragma unroll
  for (int mi = 0; mi < 4; ++mi)
    aptr[mi] = zq + (size_t)(rowA + wm * 64 + mi * 16 + c16) * KD + quad * 32;
#pragma unroll
  for (int ni = 0; ni < 4; ++ni)
    bptr[ni] = zq + (size_t)(rowB + wn * 64 + ni * 16 + c16) * KD + quad * 32;

  f32x4 acc[4][4] = {};

#pragma unroll
  for (int k0 = 0; k0 < KD; k0 += BK) {
    i32x8 af[4], bg[4];
#pragma unroll
    for (int mi = 0; mi < 4; ++mi) {
      const i32x4 lo = *(const i32x4*)(aptr[mi] + k0);
      const i32x4 hi = *(const i32x4*)(aptr[mi] + k0 + 16);
      af[mi] = (i32x8){lo[0], lo[1], lo[2], lo[3], hi[0], hi[1], hi[2], hi[3]};
    }
#pragma unroll
    for (int ni = 0; ni < 4; ++ni) {
      const i32x4 lo = *(const i32x4*)(bptr[ni] + k0);
      const i32x4 hi = *(const i32x4*)(bptr[ni] + k0 + 16);
      bg[ni] = (i32x8){lo[0], lo[1], lo[2], lo[3], hi[0], hi[1], hi[2], hi[3]};
    }
#pragma unroll
    for (int mi = 0; mi < 4; ++mi)
#pragma unroll
      for (int ni = 0; ni < 4; ++ni)
        acc[mi][ni] = __builtin_amdgcn_mfma_scale_f32_16x16x128_f8f6f4(
            af[mi], bg[ni], acc[mi][ni],
            0, 0,                    // cbsz=fp8(e4m3), blgp=fp8(e4m3)
            0, 0x7F7F7F7F,           // scale A: opsel 0, E8M0 1.0
            0, 0x7F7F7F7F);          // scale B: opsel 0, E8M0 1.0
  }

  // in-tile diagonal ownership: row(quad*4+r) == col(c16) <=> quad==c16>>2, r==c16&3
  const bool ownDiag = (quad == (c16 >> 2));
  const int rdiag = c16 & 3;

  // ---- positive pairs (pre-exp): sum 4*dot over this block's diagonal ----
  if (isPos && wm == wn) {
    float p = 0.f;
    if (ownDiag) {
#pragma unroll
      for (int mi = 0; mi < 4; ++mi) p += acc[mi][mi][rdiag];
    }
#pragma unroll
    for (int m = 1; m < 64; m <<= 1) p += __shfl_xor(p, m);
    if (lane == 0) atomicAdd(possum, 4.0f * p);
  }

  // ---- e = exp(2*sim) in place ----
#pragma unroll
  for (int mi = 0; mi < 4; ++mi)
#pragma unroll
    for (int ni = 0; ni < 4; ++ni)
#pragma unroll
      for (int r = 0; r < 4; ++r)
        acc[mi][ni][r] = __expf(2.0f * acc[mi][ni][r]);

  // ---- diagonal removal (diag blocks): zero exp(sim_ii) ----
  if (diag && wm == wn && ownDiag) {
#pragma unroll
    for (int mi = 0; mi < 4; ++mi) acc[mi][mi][rdiag] = 0.f;
  }

  if (t < TILE) { lrow[t] = 0.f; lcol[t] = 0.f; }
  __syncthreads();

  // row sums: reduce over ni (in-register) and c16 (shfl over lane bits 0-3)
#pragma unroll
  for (int mi = 0; mi < 4; ++mi) {
#pragma unroll
    for (int r = 0; r < 4; ++r) {
      float e = acc[mi][0][r] + acc[mi][1][r] + acc[mi][2][r] + acc[mi][3][r];
      e += __shfl_xor(e, 1);
      e += __shfl_xor(e, 2);
      e += __shfl_xor(e, 4);
      e += __shfl_xor(e, 8);
      if (c16 == 0) atomicAdd(&lrow[wm * 64 + mi * 16 + quad * 4 + r], e);
    }
  }
  // col sums: reduce over mi,r (in-register) and quad (shfl over lane bits 4-5)
  if (!diag) {
#pragma unroll
    for (int ni = 0; ni < 4; ++ni) {
      float g = 0.f;
#pragma unroll
      for (int mi = 0; mi < 4; ++mi)
#pragma unroll
        for (int r = 0; r < 4; ++r) g += acc[mi][ni][r];
      g += __shfl_xor(g, 16);
      g += __shfl_xor(g, 32);
      if (quad == 0) atomicAdd(&lcol[wn * 64 + ni * 16 + c16], g);
    }
  }
  __syncthreads();
  if (t < TILE) {
    atomicAdd(&rowsum[rowA + t], lrow[t]);
    if (!diag) atomicAdd(&rowsum[rowB + t], lcol[t]);
  }
}

// ---------------- finalize: loss = (sum_i log(rowsum_i) - possum) / NROWS ----
__global__ __launch_bounds__(256) void nt_finalize(const float* __restrict__ rowsum,
                                                   const float* __restrict__ possum,
                                                   float* __restrict__ out) {
  const int t = threadIdx.x;
  const int i = blockIdx.x * 256 + t;
  float v = logf(rowsum[i]);
#pragma unroll
  for (int m = 1; m < 64; m <<= 1) v += __shfl_xor(v, m);
  __shared__ float bsum[4];
  if ((t & 63) == 0) bsum[t >> 6] = v;
  __syncthreads();
  if (t == 0) {
    float s = bsum[0] + bsum[1] + bsum[2] + bsum[3];
    if (blockIdx.x == 0) s -= possum[0];
    atomicAdd(out, s * (1.0f / NROWS));
  }
}

extern "C" void kernel_launch(void* const* d_in, const int* in_sizes, int n_in,
                              void* d_out, int out_size, void* d_ws, size_t ws_size,
                              hipStream_t stream) {
  const float* zi = (const float*)d_in[0];
  const float* zj = (const float*)d_in[1];
  float* out = (float*)d_out;

  // ws layout: zq (8192*512 fp8 = 4 MB) | rowsum (8192 f32) | possum (1 f32)
  u8* zq = (u8*)d_ws;
  float* rowsum = (float*)((char*)d_ws + (size_t)NROWS * KD);
  float* possum = rowsum + NROWS;

  nt_normalize<<<NROWS / 4, 256, 0, stream>>>(zi, zj, zq, rowsum, possum, out);
  nt_gemm<<<NT * (NT + 1) / 2, 256, 0, stream>>>(zq, rowsum, possum);
  nt_finalize<<<NROWS / 256, 256, 0, stream>>>(rowsum, possum, out);
}